// Round 3
// baseline (167.111 us; speedup 1.0000x reference)
//
#include <hip/hip_runtime.h>
#include <hip/hip_bf16.h>

#define N 4096
#define HID 256
#define NH 8
#define HD 32
#define NC 784    // 256 Q | 256 K | 256 V | 16 EG
#define CH 8      // j-chunks; ws proven >= 41 MB (round-2 ran CH=8)
#define JSPAN (N / CH)
#define PSTR 72   // ushorts per P row (144 B: 16B-aligned, 2-way banks = free)

typedef __attribute__((ext_vector_type(8))) short short8;
typedef __attribute__((ext_vector_type(4))) short short4v;
typedef __attribute__((ext_vector_type(4))) float f32x4;

static __device__ __forceinline__ unsigned short f2bf(float f) {
    union { float f; unsigned u; } v; v.f = f;
    unsigned r = v.u + 0x7fff + ((v.u >> 16) & 1);
    return (unsigned short)(r >> 16);
}
static __device__ __forceinline__ unsigned packbf2(float a, float b) {
    __hip_bfloat162 t = __float22bfloat162_rn(make_float2(a, b));
    unsigned u; __builtin_memcpy(&u, &t, 4); return u;
}

// ---- fused prep: feat->bf16 (blocks 0..1023) | WbT/bC build + colS zero ----
__global__ void k_prep(const float* __restrict__ feat, const float* __restrict__ Wq,
                       const float* __restrict__ Wkv, const float* __restrict__ Weg,
                       const float* __restrict__ bq, const float* __restrict__ bkv,
                       const float* __restrict__ beg, unsigned short* __restrict__ featb,
                       unsigned short* __restrict__ WbT, float* __restrict__ bC,
                       float* __restrict__ colS) {
    int bx = blockIdx.x;
    if (bx < 1024) {
        int t = bx * 256 + threadIdx.x;
        float4 v = ((const float4*)feat)[t];
        short4v o;
        o[0] = (short)f2bf(v.x); o[1] = (short)f2bf(v.y);
        o[2] = (short)f2bf(v.z); o[3] = (short)f2bf(v.w);
        ((short4v*)featb)[t] = o;
    } else {
        int c = bx - 1024, k = threadIdx.x;
        float w, b;
        if (c < 256)      { w = Wq[k * 256 + c];          b = bq[c]; }
        else if (c < 768) { w = Wkv[k * 512 + (c - 256)]; b = bkv[c - 256]; }
        else              { w = Weg[k * 16 + (c - 768)];  b = beg[c - 768]; }
        WbT[c * 256 + k] = f2bf(w);
        if (k == 0) bC[c] = b;
        if (c < 128) colS[c * 256 + k] = 0.f;   // zero 32768 floats
    }
}

// ---- projection GEMM: [4096,256]x[256,784]; scatter into packed layouts ----
__global__ __launch_bounds__(256) void k_proj(const unsigned short* __restrict__ featb,
                                              const unsigned short* __restrict__ WbT,
                                              const float* __restrict__ bC,
                                              unsigned short* __restrict__ Qp,
                                              unsigned short* __restrict__ Kp,
                                              unsigned short* __restrict__ VpT,
                                              float* __restrict__ sigG) {
    int w = threadIdx.x >> 6, l = threadIdx.x & 63;
    int il = l & 15, g = l >> 4;
    int c0 = blockIdx.x * 16;
    int i0 = (blockIdx.y * 4 + w) * 16;
    const short8* Arow = (const short8*)(featb + (size_t)(i0 + il) * HID);
    const short8* Brow = (const short8*)(WbT + (size_t)(c0 + il) * HID);
    f32x4 acc = {0.f, 0.f, 0.f, 0.f};
#pragma unroll
    for (int k0 = 0; k0 < HID; k0 += 32) {
        short8 a = Arow[(k0 >> 3) + g];
        short8 b = Brow[(k0 >> 3) + g];
        acc = __builtin_amdgcn_mfma_f32_16x16x32_bf16(a, b, acc, 0, 0, 0);
    }
    int c = c0 + il;
    float bias = bC[c];
#pragma unroll
    for (int r = 0; r < 4; ++r) {
        int i = i0 + g * 4 + r;
        float val = acc[r] + bias;
        if (c < 256) {
            int h = c & 7, d = c >> 3;
            Qp[((size_t)h * N + i) * HD + d] = f2bf(val * 0.17677669529663687f);
        } else if (c < 512) {
            int cc = c - 256, h = cc & 7, d = cc >> 3;
            Kp[((size_t)h * N + i) * HD + d] = f2bf(val);
        } else if (c < 768) {
            int cc = c - 512, h = cc & 7, d = cc >> 3;
            VpT[((size_t)h * HD + d) * N + i] = f2bf(val);
        } else {
            int cc = c - 768;
            if (cc >= 8) sigG[(size_t)(cc - 8) * N + i] = 1.f / (1.f + __expf(-val));
        }
    }
}

// ---- pass 1: colS[j,h] += sum_i exp(S_ij); j-tile 32 (2 Kf per Q-load) ----
__global__ __launch_bounds__(256) void k_pass1(const unsigned short* __restrict__ Qp,
                                               const unsigned short* __restrict__ Kp,
                                               float* __restrict__ colS) {
    int w = threadIdx.x >> 6, l = threadIdx.x & 63;
    int il = l & 15, g = l >> 4;
    int h = blockIdx.y;
    int j0 = (blockIdx.x * 4 + w) * 32;
    const unsigned short* Kh = Kp + (size_t)h * N * HD;
    short8 Kf0 = *(const short8*)(Kh + (size_t)(j0 + il) * HD + g * 8);
    short8 Kf1 = *(const short8*)(Kh + (size_t)(j0 + 16 + il) * HD + g * 8);
    const unsigned short* Qh = Qp + (size_t)h * N * HD;
    f32x4 z = {0.f, 0.f, 0.f, 0.f};
    float s0 = 0.f, s1 = 0.f;
    int ibeg = blockIdx.z * 512, iend = ibeg + 512;
    for (int i0 = ibeg; i0 < iend; i0 += 16) {
        short8 Qf = *(const short8*)(Qh + (size_t)(i0 + il) * HD + g * 8);
        f32x4 Sa = __builtin_amdgcn_mfma_f32_16x16x32_bf16(Qf, Kf0, z, 0, 0, 0);
        f32x4 Sb = __builtin_amdgcn_mfma_f32_16x16x32_bf16(Qf, Kf1, z, 0, 0, 0);
        s0 += (__expf(Sa[0]) + __expf(Sa[1])) + (__expf(Sa[2]) + __expf(Sa[3]));
        s1 += (__expf(Sb[0]) + __expf(Sb[1])) + (__expf(Sb[2]) + __expf(Sb[3]));
    }
#pragma unroll
    for (int off = 16; off <= 32; off <<= 1) {
        s0 += __shfl_xor(s0, off);
        s1 += __shfl_xor(s1, off);
    }
    if (g == 0) {
        atomicAdd(&colS[(size_t)h * N + j0 + il], s0);
        atomicAdd(&colS[(size_t)h * N + j0 + 16 + il], s1);
    }
}

// ---- pass 2: Vpart[z][h][i][d] = sum_{j in chunk z} exp(S+lc[j]) * V[j,d] ----
__global__ __launch_bounds__(256) void k_pass2(const unsigned short* __restrict__ Qp,
                                               const unsigned short* __restrict__ Kp,
                                               const unsigned short* __restrict__ VpT,
                                               const float* __restrict__ sigG,
                                               const float* __restrict__ colS,
                                               float* __restrict__ Vpart) {
    __shared__ __align__(16) unsigned short Pl[4][16 * PSTR];  // per-wave, no barriers
    __shared__ __align__(16) float LC[4][JSPAN];
    int w = threadIdx.x >> 6, l = threadIdx.x & 63;
    int il = l & 15, g = l >> 4;
    int h = blockIdx.y;
    int jbeg = blockIdx.z * JSPAN;
    const float* sg = sigG + (size_t)h * N + jbeg;
    const float* cs = colS + (size_t)h * N + jbeg;
    float* lcw = LC[w];
    for (int t = l; t < JSPAN; t += 64) lcw[t] = __logf(sg[t] / cs[t]);
    int i0 = (blockIdx.x * 4 + w) * 16;
    const unsigned short* Kh = Kp + (size_t)h * N * HD;
    const unsigned short* Vh = VpT + (size_t)h * HD * N + jbeg;
    short8 Qf = *(const short8*)(Qp + ((size_t)h * N + i0 + il) * HD + g * 8);
    f32x4 acc0 = {0.f, 0.f, 0.f, 0.f}, acc1 = acc0;
    unsigned short* P = Pl[w];
    for (int jb = 0; jb < JSPAN; jb += 64) {
#pragma unroll
        for (int s = 0; s < 2; ++s) {
#pragma unroll
            for (int hf = 0; hf < 2; ++hf) {
                int jloc = jb + s * 32 + hf * 16;
                short8 Kf = *(const short8*)(Kh + (size_t)(jbeg + jloc + il) * HD + g * 8);
                f32x4 lcv = *(const f32x4*)(lcw + jloc + g * 4);
                f32x4 S = __builtin_amdgcn_mfma_f32_16x16x32_bf16(Kf, Qf, lcv, 0, 0, 0);
                unsigned* dst = (unsigned*)(P + (size_t)il * PSTR + s * 32 + hf * 16 + g * 4);
                dst[0] = packbf2(__expf(S[0]), __expf(S[1]));
                dst[1] = packbf2(__expf(S[2]), __expf(S[3]));
            }
        }
#pragma unroll
        for (int s = 0; s < 2; ++s) {
            short8 Pa  = *(const short8*)(P + (size_t)il * PSTR + s * 32 + g * 8);
            short8 Vb0 = *(const short8*)(Vh + (size_t)il * N + jb + s * 32 + g * 8);
            short8 Vb1 = *(const short8*)(Vh + (size_t)(16 + il) * N + jb + s * 32 + g * 8);
            acc0 = __builtin_amdgcn_mfma_f32_16x16x32_bf16(Pa, Vb0, acc0, 0, 0, 0);
            acc1 = __builtin_amdgcn_mfma_f32_16x16x32_bf16(Pa, Vb1, acc1, 0, 0, 0);
        }
    }
    float* Vout = Vpart + (size_t)(blockIdx.z * NH + h) * N * HD;
#pragma unroll
    for (int r = 0; r < 4; ++r) {
        int ia = i0 + g * 4 + r;
        Vout[(size_t)ia * HD + il]      = acc0[r];
        Vout[(size_t)ia * HD + 16 + il] = acc1[r];
    }
}

// ---- layernorm: sum CH partials (layout [ch][h][i][d]), normalize, scatter ----
__global__ __launch_bounds__(256) void k_ln(const float* __restrict__ Vpart,
                                            const float* __restrict__ gam,
                                            const float* __restrict__ bet,
                                            float* __restrict__ out) {
    int w = threadIdx.x >> 6, l = threadIdx.x & 63;
    int i = blockIdx.x * 4 + w;
    int h = l >> 3, d0 = (l & 7) << 2;   // lane owns channels c = (d0+r)*8 + h
    f32x4 x = {0.f, 0.f, 0.f, 0.f};
#pragma unroll
    for (int c = 0; c < CH; ++c) {
        f32x4 v = *(const f32x4*)(Vpart + ((size_t)(c * NH + h) * N + i) * HD + d0);
        x[0] += v[0]; x[1] += v[1]; x[2] += v[2]; x[3] += v[3];
    }
    float s1 = x[0] + x[1] + x[2] + x[3];
    float s2 = x[0] * x[0] + x[1] * x[1] + x[2] * x[2] + x[3] * x[3];
#pragma unroll
    for (int off = 1; off < 64; off <<= 1) {
        s1 += __shfl_xor(s1, off);
        s2 += __shfl_xor(s2, off);
    }
    float mu = s1 * (1.f / 256.f);
    float var = s2 * (1.f / 256.f) - mu * mu;
    float rs = rsqrtf(var + 1e-3f);
#pragma unroll
    for (int r = 0; r < 4; ++r) {
        int c = (d0 + r) * 8 + h;
        out[(size_t)i * HID + c] = (x[r] - mu) * rs * gam[c] + bet[c];
    }
}

extern "C" void kernel_launch(void* const* d_in, const int* in_sizes, int n_in,
                              void* d_out, int out_size, void* d_ws, size_t ws_size,
                              hipStream_t stream) {
    const float* feat = (const float*)d_in[0];
    const float* Wq   = (const float*)d_in[1];
    const float* bq   = (const float*)d_in[2];
    const float* Wkv  = (const float*)d_in[3];
    const float* bkv  = (const float*)d_in[4];
    const float* Weg  = (const float*)d_in[5];
    const float* beg  = (const float*)d_in[6];
    const float* ln_g = (const float*)d_in[7];
    const float* ln_b = (const float*)d_in[8];
    float* out = (float*)d_out;

    char* ws = (char*)d_ws;
    unsigned short* Qp    = (unsigned short*)(ws + 0);                     // 2 MB
    unsigned short* Kp    = (unsigned short*)(ws + (2u << 20));            // 2 MB
    unsigned short* VpT   = (unsigned short*)(ws + (4u << 20));            // 2 MB
    unsigned short* featb = (unsigned short*)(ws + (6u << 20));            // 2 MB
    unsigned short* WbT   = (unsigned short*)(ws + (8u << 20));            // 0.4 MB
    float* bC   = (float*)(ws + (8u << 20) + (512u << 10));                // 3 KB
    float* sigG = (float*)(ws + (8u << 20) + (528u << 10));                // 128 KB
    float* colS = (float*)(ws + (8u << 20) + (656u << 10));                // 128 KB
    float* Vpart = (float*)(ws + (9u << 20));                              // CH*4 MB

    k_prep<<<dim3(1024 + NC), 256, 0, stream>>>(feat, Wq, Wkv, Weg, bq, bkv, beg,
                                                featb, WbT, bC, colS);
    k_proj<<<dim3(49, 64), 256, 0, stream>>>(featb, WbT, bC, Qp, Kp, VpT, sigG);
    k_pass1<<<dim3(32, NH, 8), 256, 0, stream>>>(Qp, Kp, colS);
    k_pass2<<<dim3(64, NH, CH), 256, 0, stream>>>(Qp, Kp, VpT, sigG, colS, Vpart);
    k_ln<<<dim3(1024), 256, 0, stream>>>(Vpart, ln_g, ln_b, out);
}

// Round 4
// 127.360 us; speedup vs baseline: 1.3121x; 1.3121x over previous
//
#include <hip/hip_runtime.h>
#include <hip/hip_bf16.h>

#define N 4096
#define HID 256
#define NH 8
#define HD 32
#define NC 784    // 256 Q | 256 K | 256 V | 16 EG
#define CH 8      // j-chunks (ws >= 41 MB proven in round 2/3)
#define JSPAN (N / CH)
#define PSTR 40   // P-row stride in ushorts (80B: 16B-aligned b128, 2-way banks = free)

typedef __attribute__((ext_vector_type(8))) short short8;
typedef __attribute__((ext_vector_type(4))) short short4v;
typedef __attribute__((ext_vector_type(4))) float f32x4;

// Q scale = (1/sqrt(32)) * log2(e): folds softmax temp AND exp->exp2 conversion
#define QSCALE 0.25503482f

static __device__ __forceinline__ unsigned short f2bf(float f) {
    union { float f; unsigned u; } v; v.f = f;
    unsigned r = v.u + 0x7fff + ((v.u >> 16) & 1);
    return (unsigned short)(r >> 16);
}
static __device__ __forceinline__ unsigned packbf2(float a, float b) {
    __hip_bfloat162 t = __float22bfloat162_rn(make_float2(a, b));
    unsigned u; __builtin_memcpy(&u, &t, 4); return u;
}

// ---- fused prep: feat->bf16 (blocks 0..1023) | WbT/bC build + colS zero ----
__global__ void k_prep(const float* __restrict__ feat, const float* __restrict__ Wq,
                       const float* __restrict__ Wkv, const float* __restrict__ Weg,
                       const float* __restrict__ bq, const float* __restrict__ bkv,
                       const float* __restrict__ beg, unsigned short* __restrict__ featb,
                       unsigned short* __restrict__ WbT, float* __restrict__ bC,
                       float* __restrict__ colS) {
    int bx = blockIdx.x;
    if (bx < 1024) {
        int t = bx * 256 + threadIdx.x;
        float4 v = ((const float4*)feat)[t];
        short4v o;
        o[0] = (short)f2bf(v.x); o[1] = (short)f2bf(v.y);
        o[2] = (short)f2bf(v.z); o[3] = (short)f2bf(v.w);
        ((short4v*)featb)[t] = o;
    } else {
        int c = bx - 1024, k = threadIdx.x;
        float w, b;
        if (c < 256)      { w = Wq[k * 256 + c];          b = bq[c]; }
        else if (c < 768) { w = Wkv[k * 512 + (c - 256)]; b = bkv[c - 256]; }
        else              { w = Weg[k * 16 + (c - 768)];  b = beg[c - 768]; }
        WbT[c * 256 + k] = f2bf(w);
        if (k == 0) bC[c] = b;
        if (c < 128) colS[c * 256 + k] = 0.f;
    }
}

// ---- projection GEMM: [4096,256]x[256,784]; scatter into packed layouts ----
__global__ __launch_bounds__(256) void k_proj(const unsigned short* __restrict__ featb,
                                              const unsigned short* __restrict__ WbT,
                                              const float* __restrict__ bC,
                                              unsigned short* __restrict__ Qp,
                                              unsigned short* __restrict__ Kp,
                                              unsigned short* __restrict__ VpT,
                                              float* __restrict__ sigG) {
    int w = threadIdx.x >> 6, l = threadIdx.x & 63;
    int il = l & 15, g = l >> 4;
    int c0 = blockIdx.x * 16;
    int i0 = (blockIdx.y * 4 + w) * 16;
    const short8* Arow = (const short8*)(featb + (size_t)(i0 + il) * HID);
    const short8* Brow = (const short8*)(WbT + (size_t)(c0 + il) * HID);
    f32x4 acc = {0.f, 0.f, 0.f, 0.f};
#pragma unroll
    for (int k0 = 0; k0 < HID; k0 += 32) {
        short8 a = Arow[(k0 >> 3) + g];
        short8 b = Brow[(k0 >> 3) + g];
        acc = __builtin_amdgcn_mfma_f32_16x16x32_bf16(a, b, acc, 0, 0, 0);
    }
    int c = c0 + il;
    float bias = bC[c];
#pragma unroll
    for (int r = 0; r < 4; ++r) {
        int i = i0 + g * 4 + r;
        float val = acc[r] + bias;
        if (c < 256) {
            int h = c & 7, d = c >> 3;
            Qp[((size_t)h * N + i) * HD + d] = f2bf(val * QSCALE);
        } else if (c < 512) {
            int cc = c - 256, h = cc & 7, d = cc >> 3;
            Kp[((size_t)h * N + i) * HD + d] = f2bf(val);
        } else if (c < 768) {
            int cc = c - 512, h = cc & 7, d = cc >> 3;
            VpT[((size_t)h * HD + d) * N + i] = f2bf(val);
        } else {
            int cc = c - 768;
            if (cc >= 8) sigG[(size_t)(cc - 8) * N + i] = 1.f / (1.f + __expf(-val));
        }
    }
}

// ---- pass 1: colS[j,h] += sum_i 2^(S2_ij)  (Q prescaled by log2e) ----
// grid (32, NH, 8): x*4+w = j-tile of 32, z = i-chunk of 512
__global__ __launch_bounds__(256) void k_pass1(const unsigned short* __restrict__ Qp,
                                               const unsigned short* __restrict__ Kp,
                                               float* __restrict__ colS) {
    int w = threadIdx.x >> 6, l = threadIdx.x & 63;
    int il = l & 15, g = l >> 4;
    int h = blockIdx.y;
    int j0 = (blockIdx.x * 4 + w) * 32;
    const unsigned short* Kh = Kp + (size_t)h * N * HD;
    short8 Kf0 = *(const short8*)(Kh + (size_t)(j0 + il) * HD + g * 8);
    short8 Kf1 = *(const short8*)(Kh + (size_t)(j0 + 16 + il) * HD + g * 8);
    const unsigned short* Qh = Qp + (size_t)h * N * HD;
    f32x4 z = {0.f, 0.f, 0.f, 0.f};
    float s0 = 0.f, s1 = 0.f;
    int ibeg = blockIdx.z * 512, iend = ibeg + 512;
    for (int i0 = ibeg; i0 < iend; i0 += 16) {
        short8 Qf = *(const short8*)(Qh + (size_t)(i0 + il) * HD + g * 8);
        f32x4 Sa = __builtin_amdgcn_mfma_f32_16x16x32_bf16(Qf, Kf0, z, 0, 0, 0);
        f32x4 Sb = __builtin_amdgcn_mfma_f32_16x16x32_bf16(Qf, Kf1, z, 0, 0, 0);
        s0 += (__builtin_amdgcn_exp2f(Sa[0]) + __builtin_amdgcn_exp2f(Sa[1]))
            + (__builtin_amdgcn_exp2f(Sa[2]) + __builtin_amdgcn_exp2f(Sa[3]));
        s1 += (__builtin_amdgcn_exp2f(Sb[0]) + __builtin_amdgcn_exp2f(Sb[1]))
            + (__builtin_amdgcn_exp2f(Sb[2]) + __builtin_amdgcn_exp2f(Sb[3]));
    }
#pragma unroll
    for (int off = 16; off <= 32; off <<= 1) {
        s0 += __shfl_xor(s0, off);
        s1 += __shfl_xor(s1, off);
    }
    if (g == 0) {
        atomicAdd(&colS[(size_t)h * N + j0 + il], s0);
        atomicAdd(&colS[(size_t)h * N + j0 + 16 + il], s1);
    }
}

// ---- lc2 = log2(sigG / colS), 32768 elements ----
__global__ void k_lc2(const float* __restrict__ sigG, const float* __restrict__ colS,
                      float* __restrict__ lc2) {
    int t = blockIdx.x * blockDim.x + threadIdx.x;
    f32x4 a = ((const f32x4*)sigG)[t];
    f32x4 b = ((const f32x4*)colS)[t];
    f32x4 o;
#pragma unroll
    for (int r = 0; r < 4; ++r) o[r] = __builtin_amdgcn_logf(a[r] / b[r]);
    ((f32x4*)lc2)[t] = o;
}

// ---- pass 2: Vpart[z][h][i][d] = sum_{j in chunk} 2^(S2+lc2[j]) * V[j,d] ----
// grid (32, NH, CH): x*4+w = i-tile of 32 rows, z = j-chunk of 512
__global__ __launch_bounds__(256) void k_pass2(const unsigned short* __restrict__ Qp,
                                               const unsigned short* __restrict__ Kp,
                                               const unsigned short* __restrict__ VpT,
                                               const float* __restrict__ lc2,
                                               float* __restrict__ Vpart) {
    __shared__ __align__(16) unsigned short Pl[4][32 * PSTR];  // per-wave P, no barriers
    __shared__ __align__(16) float LC[JSPAN];                   // block-shared lc2 slice
    int w = threadIdx.x >> 6, l = threadIdx.x & 63;
    int il = l & 15, g = l >> 4;
    int h = blockIdx.y;
    int i0 = (blockIdx.x * 4 + w) * 32;
    int jbeg = blockIdx.z * JSPAN;
    // cooperative lc2 slice load (one barrier total)
    {
        const float* src = lc2 + (size_t)h * N + jbeg;
        f32x4 v = ((const f32x4*)src)[threadIdx.x];
        ((f32x4*)LC)[threadIdx.x] = v;
    }
    __syncthreads();
    const unsigned short* Qh = Qp + (size_t)h * N * HD;
    const unsigned short* Kh = Kp + (size_t)h * N * HD;
    const unsigned short* Vh = VpT + (size_t)h * HD * N + jbeg;
    short8 Qf0 = *(const short8*)(Qh + (size_t)(i0 + il) * HD + g * 8);
    short8 Qf1 = *(const short8*)(Qh + (size_t)(i0 + 16 + il) * HD + g * 8);
    f32x4 zz = {0.f, 0.f, 0.f, 0.f};
    f32x4 acc00 = zz, acc01 = zz, acc10 = zz, acc11 = zz;
    unsigned short* P = Pl[w];
    for (int jb = 0; jb < JSPAN; jb += 32) {
#pragma unroll
        for (int half = 0; half < 2; ++half) {
            int jloc = jb + half * 16;
            short8 Kf = *(const short8*)(Kh + (size_t)(jbeg + jloc + il) * HD + g * 8);
            f32x4 lcv = *(const f32x4*)(LC + jloc + g * 4);
            // swapped: D[j][i] = K·Q^T + lc2 ; lane holds j = jloc+4g+r, i = il
            f32x4 S0 = __builtin_amdgcn_mfma_f32_16x16x32_bf16(Kf, Qf0, lcv, 0, 0, 0);
            f32x4 S1 = __builtin_amdgcn_mfma_f32_16x16x32_bf16(Kf, Qf1, lcv, 0, 0, 0);
            unsigned* dst0 = (unsigned*)(P + (size_t)il * PSTR + half * 16 + g * 4);
            dst0[0] = packbf2(__builtin_amdgcn_exp2f(S0[0]), __builtin_amdgcn_exp2f(S0[1]));
            dst0[1] = packbf2(__builtin_amdgcn_exp2f(S0[2]), __builtin_amdgcn_exp2f(S0[3]));
            unsigned* dst1 = (unsigned*)(P + (size_t)(16 + il) * PSTR + half * 16 + g * 4);
            dst1[0] = packbf2(__builtin_amdgcn_exp2f(S1[0]), __builtin_amdgcn_exp2f(S1[1]));
            dst1[1] = packbf2(__builtin_amdgcn_exp2f(S1[2]), __builtin_amdgcn_exp2f(S1[3]));
        }
        short8 Pa0 = *(const short8*)(P + (size_t)il * PSTR + g * 8);
        short8 Pa1 = *(const short8*)(P + (size_t)(16 + il) * PSTR + g * 8);
        short8 Vb0 = *(const short8*)(Vh + (size_t)il * N + jb + g * 8);
        short8 Vb1 = *(const short8*)(Vh + (size_t)(16 + il) * N + jb + g * 8);
        acc00 = __builtin_amdgcn_mfma_f32_16x16x32_bf16(Pa0, Vb0, acc00, 0, 0, 0);
        acc01 = __builtin_amdgcn_mfma_f32_16x16x32_bf16(Pa0, Vb1, acc01, 0, 0, 0);
        acc10 = __builtin_amdgcn_mfma_f32_16x16x32_bf16(Pa1, Vb0, acc10, 0, 0, 0);
        acc11 = __builtin_amdgcn_mfma_f32_16x16x32_bf16(Pa1, Vb1, acc11, 0, 0, 0);
    }
    float* Vout = Vpart + (size_t)(blockIdx.z * NH + h) * N * HD;
#pragma unroll
    for (int r = 0; r < 4; ++r) {
        int ia = i0 + g * 4 + r, ib = i0 + 16 + g * 4 + r;
        Vout[(size_t)ia * HD + il]      = acc00[r];   // coalesced 64B per quarter-wave
        Vout[(size_t)ia * HD + 16 + il] = acc01[r];
        Vout[(size_t)ib * HD + il]      = acc10[r];
        Vout[(size_t)ib * HD + 16 + il] = acc11[r];
    }
}

// ---- layernorm: sum CH partials (layout [ch][h][i][d]), normalize, scatter ----
__global__ __launch_bounds__(256) void k_ln(const float* __restrict__ Vpart,
                                            const float* __restrict__ gam,
                                            const float* __restrict__ bet,
                                            float* __restrict__ out) {
    int w = threadIdx.x >> 6, l = threadIdx.x & 63;
    int i = blockIdx.x * 4 + w;
    int h = l >> 3, d0 = (l & 7) << 2;   // lane owns channels c = (d0+r)*8 + h
    f32x4 x = {0.f, 0.f, 0.f, 0.f};
#pragma unroll
    for (int c = 0; c < CH; ++c) {
        f32x4 v = *(const f32x4*)(Vpart + ((size_t)(c * NH + h) * N + i) * HD + d0);
        x[0] += v[0]; x[1] += v[1]; x[2] += v[2]; x[3] += v[3];
    }
    float s1 = x[0] + x[1] + x[2] + x[3];
    float s2 = x[0] * x[0] + x[1] * x[1] + x[2] * x[2] + x[3] * x[3];
#pragma unroll
    for (int off = 1; off < 64; off <<= 1) {
        s1 += __shfl_xor(s1, off);
        s2 += __shfl_xor(s2, off);
    }
    float mu = s1 * (1.f / 256.f);
    float var = s2 * (1.f / 256.f) - mu * mu;
    float rs = rsqrtf(var + 1e-3f);
#pragma unroll
    for (int r = 0; r < 4; ++r) {
        int c = (d0 + r) * 8 + h;
        out[(size_t)i * HID + c] = (x[r] - mu) * rs * gam[c] + bet[c];
    }
}

extern "C" void kernel_launch(void* const* d_in, const int* in_sizes, int n_in,
                              void* d_out, int out_size, void* d_ws, size_t ws_size,
                              hipStream_t stream) {
    const float* feat = (const float*)d_in[0];
    const float* Wq   = (const float*)d_in[1];
    const float* bq   = (const float*)d_in[2];
    const float* Wkv  = (const float*)d_in[3];
    const float* bkv  = (const float*)d_in[4];
    const float* Weg  = (const float*)d_in[5];
    const float* beg  = (const float*)d_in[6];
    const float* ln_g = (const float*)d_in[7];
    const float* ln_b = (const float*)d_in[8];
    float* out = (float*)d_out;

    char* ws = (char*)d_ws;
    unsigned short* Qp    = (unsigned short*)(ws + 0);                     // 2 MB
    unsigned short* Kp    = (unsigned short*)(ws + (2u << 20));            // 2 MB
    unsigned short* VpT   = (unsigned short*)(ws + (4u << 20));            // 2 MB
    unsigned short* featb = (unsigned short*)(ws + (6u << 20));            // 2 MB
    unsigned short* WbT   = (unsigned short*)(ws + (8u << 20));            // 0.4 MB
    float* bC   = (float*)(ws + (8u << 20) + (512u << 10));                // 3 KB
    float* sigG = (float*)(ws + (8u << 20) + (528u << 10));                // 128 KB
    float* colS = (float*)(ws + (8u << 20) + (656u << 10));                // 128 KB
    float* lc2  = (float*)(ws + (8u << 20) + (784u << 10));                // 128 KB
    float* Vpart = (float*)(ws + (9u << 20));                              // CH*4 MB

    k_prep<<<dim3(1024 + NC), 256, 0, stream>>>(feat, Wq, Wkv, Weg, bq, bkv, beg,
                                                featb, WbT, bC, colS);
    k_proj<<<dim3(49, 64), 256, 0, stream>>>(featb, WbT, bC, Qp, Kp, VpT, sigG);
    k_pass1<<<dim3(32, NH, 8), 256, 0, stream>>>(Qp, Kp, colS);
    k_lc2<<<dim3(32), 256, 0, stream>>>(sigG, colS, lc2);
    k_pass2<<<dim3(32, NH, CH), 256, 0, stream>>>(Qp, Kp, VpT, lc2, Vpart);
    k_ln<<<dim3(1024), 256, 0, stream>>>(Vpart, ln_g, ln_b, out);
}